// Round 1
// baseline (61.659 us; speedup 1.0000x reference)
//
#include <hip/hip_runtime.h>
#include <math.h>

#define SIZE 1024
#define BATCH 32
#define SEQ 2048
#define PARTS 4          // e-dim split for k_project parallelism
#define EPART (SIZE / PARTS)

// ---------------------------------------------------------------------------
// Kernel 1: partial projection  vpart[part][b][d] = sum_{e in part} dh[b,e]*W[e,d]
// Thread owns one (part, b, d4) where d4 indexes a float4 column group.
// 32768 threads = 128 blocks x 256. W loads coalesced float4; W (4MB) is L2-resident.
// ---------------------------------------------------------------------------
__global__ __launch_bounds__(256) void k_project(const float* __restrict__ dh,
                                                 const float* __restrict__ W,
                                                 float* __restrict__ vpart) {
    int tid  = blockIdx.x * 256 + threadIdx.x;      // 0 .. 32767
    int part = tid >> 13;                            // 0..3
    int rem  = tid & 8191;
    int b    = rem >> 8;                             // 0..31
    int d4   = rem & 255;                            // 0..255 (float4 granule)

    const float4* W4  = (const float4*)W;            // [SIZE][SIZE/4]
    const float*  dhb = dh + b * SIZE;
    int e0 = part * EPART;

    float4 acc = make_float4(0.f, 0.f, 0.f, 0.f);
    #pragma unroll 8
    for (int e = e0; e < e0 + EPART; ++e) {
        float  s = dhb[e];                           // wave-uniform scalar
        float4 w = W4[e * (SIZE / 4) + d4];
        acc.x += s * w.x;
        acc.y += s * w.y;
        acc.z += s * w.z;
        acc.w += s * w.w;
    }
    ((float4*)vpart)[(part * BATCH + b) * (SIZE / 4) + d4] = acc;
}

// ---------------------------------------------------------------------------
// Kernel 2: v[b][d] = sum over parts of vpart. 8192 float4 elems, 32 blocks.
// ---------------------------------------------------------------------------
__global__ __launch_bounds__(256) void k_reduce(const float* __restrict__ vpart,
                                                float* __restrict__ v) {
    int i = blockIdx.x * 256 + threadIdx.x;          // 0 .. 8191 (float4 index)
    const float4* vp = (const float4*)vpart;
    float4 a = vp[i];
    #pragma unroll
    for (int p = 1; p < PARTS; ++p) {
        float4 t = vp[p * BATCH * (SIZE / 4) + i];
        a.x += t.x; a.y += t.y; a.z += t.z; a.w += t.w;
    }
    ((float4*)v)[i] = a;
}

// ---------------------------------------------------------------------------
// Kernel 3: energies[b][s] = v[b] . enc[s][b][:]
// One wave per (s,b) pair. Lane reads 4 float4s (stride 64 float4s) -> the
// 1024-float row is covered by fully-coalesced 1KB/wave transactions.
// 65536 waves = 16384 blocks x 256 (4 waves/block; consecutive waves share s,
// adjacent b -> good L2 locality). This kernel carries the 256 MiB HBM read.
// ---------------------------------------------------------------------------
__global__ __launch_bounds__(256) void k_energies(const float* __restrict__ enc,
                                                  const float* __restrict__ v,
                                                  float* __restrict__ energies) {
    int wave = blockIdx.x * 4 + (threadIdx.x >> 6);
    int lane = threadIdx.x & 63;
    int s = wave >> 5;                               // 0..2047
    int b = wave & 31;                               // 0..31

    const float4* row = (const float4*)(enc + ((size_t)s * BATCH + b) * SIZE);
    const float4* vb  = (const float4*)(v + b * SIZE);

    float acc = 0.f;
    #pragma unroll
    for (int k = 0; k < 4; ++k) {
        float4 ev = row[lane + (k << 6)];
        float4 vv = vb[lane + (k << 6)];
        acc += ev.x * vv.x + ev.y * vv.y + ev.z * vv.z + ev.w * vv.w;
    }
    #pragma unroll
    for (int off = 32; off; off >>= 1) acc += __shfl_down(acc, off, 64);
    if (lane == 0) energies[b * SEQ + s] = acc;
}

// ---------------------------------------------------------------------------
// Kernel 4: row softmax over s. One block per b; 256 threads x 8 elems each,
// values kept in registers across the max/exp/sum passes.
// Note: the reference's "+ dh[b].bias" term is constant over s and cancels in
// softmax (shift invariance) -- bias input is intentionally unused.
// ---------------------------------------------------------------------------
__global__ __launch_bounds__(256) void k_softmax(const float* __restrict__ energies,
                                                 float* __restrict__ out) {
    int b = blockIdx.x;
    const float* row = energies + b * SEQ;
    int t = threadIdx.x;
    int wid = t >> 6, lane = t & 63;

    float vals[8];
    float m = -INFINITY;
    #pragma unroll
    for (int i = 0; i < 8; ++i) {
        vals[i] = row[t + (i << 8)];
        m = fmaxf(m, vals[i]);
    }
    __shared__ float redm[4];
    #pragma unroll
    for (int off = 32; off; off >>= 1) m = fmaxf(m, __shfl_down(m, off, 64));
    if (lane == 0) redm[wid] = m;
    __syncthreads();
    m = fmaxf(fmaxf(redm[0], redm[1]), fmaxf(redm[2], redm[3]));

    float sum = 0.f;
    #pragma unroll
    for (int i = 0; i < 8; ++i) {
        vals[i] = __expf(vals[i] - m);
        sum += vals[i];
    }
    __shared__ float reds[4];
    #pragma unroll
    for (int off = 32; off; off >>= 1) sum += __shfl_down(sum, off, 64);
    if (lane == 0) reds[wid] = sum;
    __syncthreads();
    sum = reds[0] + reds[1] + reds[2] + reds[3];

    float inv = 1.f / sum;
    #pragma unroll
    for (int i = 0; i < 8; ++i)
        out[b * SEQ + t + (i << 8)] = vals[i] * inv;
}

// ---------------------------------------------------------------------------
extern "C" void kernel_launch(void* const* d_in, const int* in_sizes, int n_in,
                              void* d_out, int out_size, void* d_ws, size_t ws_size,
                              hipStream_t stream) {
    const float* dh  = (const float*)d_in[0];   // [32, 1024]
    const float* enc = (const float*)d_in[1];   // [2048, 32, 1024]
    const float* W   = (const float*)d_in[2];   // [1024, 1024]
    // d_in[3] = bias: unused (cancels under softmax shift invariance)

    float* ws       = (float*)d_ws;
    float* vpart    = ws;                                   // PARTS*32*1024 = 131072 f
    float* v        = vpart + PARTS * BATCH * SIZE;         // 32*1024      =  32768 f
    float* energies = v + BATCH * SIZE;                     // 32*2048      =  65536 f

    k_project <<<128, 256, 0, stream>>>(dh, W, vpart);
    k_reduce  <<<32, 256, 0, stream>>>(vpart, v);
    k_energies<<<(BATCH * SEQ) / 4, 256, 0, stream>>>(enc, v, energies);
    k_softmax <<<BATCH, 256, 0, stream>>>(energies, (float*)d_out);
}

// Round 2
// 55.997 us; speedup vs baseline: 1.1011x; 1.1011x over previous
//
#include <hip/hip_runtime.h>
#include <math.h>

#define SIZE 1024
#define BATCH 32
#define SEQ 2048
#define PARTS 16         // e-dim split for k_project parallelism (2048 waves)
#define EPART (SIZE / PARTS)

// ---------------------------------------------------------------------------
// Kernel 1: partial projection  vpart[part][b][d] = sum_{e in part} dh[b,e]*W[e,d]
// Thread owns one (part, b, d4). 131072 threads = 512 blocks x 256 -> 8 waves/CU,
// 64 iters/thread: enough TLP to hide L2 latency on the W stream (W is 4MB,
// L2/L3 resident after first touch).
// ---------------------------------------------------------------------------
__global__ __launch_bounds__(256) void k_project(const float* __restrict__ dh,
                                                 const float* __restrict__ W,
                                                 float* __restrict__ vpart) {
    int tid  = blockIdx.x * 256 + threadIdx.x;      // 0 .. 131071
    int part = tid >> 13;                            // 0..15
    int rem  = tid & 8191;
    int b    = rem >> 8;                             // 0..31
    int d4   = rem & 255;                            // 0..255 (float4 granule)

    const float4* W4  = (const float4*)W;            // [SIZE][SIZE/4]
    const float*  dhb = dh + b * SIZE;
    int e0 = part * EPART;

    float4 acc = make_float4(0.f, 0.f, 0.f, 0.f);
    #pragma unroll 8
    for (int e = e0; e < e0 + EPART; ++e) {
        float  s = dhb[e];                           // wave-uniform scalar
        float4 w = W4[e * (SIZE / 4) + d4];
        acc.x += s * w.x;
        acc.y += s * w.y;
        acc.z += s * w.z;
        acc.w += s * w.w;
    }
    ((float4*)vpart)[(part * BATCH + b) * (SIZE / 4) + d4] = acc;
}

// ---------------------------------------------------------------------------
// Kernel 2: v[b][d] = sum over 16 parts of vpart. 8192 float4 elems, 32 blocks.
// vpart is 2MB -> L2-resident; ~1 us.
// ---------------------------------------------------------------------------
__global__ __launch_bounds__(256) void k_reduce(const float* __restrict__ vpart,
                                                float* __restrict__ v) {
    int i = blockIdx.x * 256 + threadIdx.x;          // 0 .. 8191 (float4 index)
    const float4* vp = (const float4*)vpart;
    float4 a = vp[i];
    #pragma unroll
    for (int p = 1; p < PARTS; ++p) {
        float4 t = vp[p * BATCH * (SIZE / 4) + i];
        a.x += t.x; a.y += t.y; a.z += t.z; a.w += t.w;
    }
    ((float4*)v)[i] = a;
}

// ---------------------------------------------------------------------------
// Kernel 3: energies[b][s] = v[b] . enc[s][b][:]
// One wave per (s-pair, b): two adjacent s rows share the v operand and give
// 8 independent 1KB enc loads in flight per wave (MLP for the HBM stream).
// 32768 waves = 8192 blocks x 256. This kernel carries the 268 MB HBM read.
// ---------------------------------------------------------------------------
__global__ __launch_bounds__(256) void k_energies(const float* __restrict__ enc,
                                                  const float* __restrict__ v,
                                                  float* __restrict__ energies) {
    int wave = blockIdx.x * 4 + (threadIdx.x >> 6);  // 0..32767
    int lane = threadIdx.x & 63;
    int b  = wave & 31;                              // 0..31
    int sp = wave >> 5;                              // 0..1023 (s-pair)
    size_t s0 = (size_t)sp * 2;

    const float4* row0 = (const float4*)(enc + (s0 * BATCH + b) * SIZE);
    const float4* row1 = (const float4*)(enc + ((s0 + 1) * BATCH + b) * SIZE);
    const float4* vb   = (const float4*)(v + b * SIZE);

    float a0 = 0.f, a1 = 0.f;
    #pragma unroll
    for (int k = 0; k < 4; ++k) {
        float4 e0 = row0[lane + (k << 6)];
        float4 e1 = row1[lane + (k << 6)];
        float4 vv = vb[lane + (k << 6)];
        a0 += e0.x * vv.x + e0.y * vv.y + e0.z * vv.z + e0.w * vv.w;
        a1 += e1.x * vv.x + e1.y * vv.y + e1.z * vv.z + e1.w * vv.w;
    }
    #pragma unroll
    for (int off = 32; off; off >>= 1) {
        a0 += __shfl_down(a0, off, 64);
        a1 += __shfl_down(a1, off, 64);
    }
    if (lane == 0)
        ((float2*)(energies + b * SEQ))[sp] = make_float2(a0, a1);
}

// ---------------------------------------------------------------------------
// Kernel 4: row softmax over s. One block per b; 256 threads x 8 elems each,
// values kept in registers across the max/exp/sum passes.
// Note: the reference's "+ dh[b].bias" term is constant over s and cancels in
// softmax (shift invariance) -- bias input is intentionally unused.
// ---------------------------------------------------------------------------
__global__ __launch_bounds__(256) void k_softmax(const float* __restrict__ energies,
                                                 float* __restrict__ out) {
    int b = blockIdx.x;
    const float* row = energies + b * SEQ;
    int t = threadIdx.x;
    int wid = t >> 6, lane = t & 63;

    float vals[8];
    float m = -INFINITY;
    #pragma unroll
    for (int i = 0; i < 8; ++i) {
        vals[i] = row[t + (i << 8)];
        m = fmaxf(m, vals[i]);
    }
    __shared__ float redm[4];
    #pragma unroll
    for (int off = 32; off; off >>= 1) m = fmaxf(m, __shfl_down(m, off, 64));
    if (lane == 0) redm[wid] = m;
    __syncthreads();
    m = fmaxf(fmaxf(redm[0], redm[1]), fmaxf(redm[2], redm[3]));

    float sum = 0.f;
    #pragma unroll
    for (int i = 0; i < 8; ++i) {
        vals[i] = __expf(vals[i] - m);
        sum += vals[i];
    }
    __shared__ float reds[4];
    #pragma unroll
    for (int off = 32; off; off >>= 1) sum += __shfl_down(sum, off, 64);
    if (lane == 0) reds[wid] = sum;
    __syncthreads();
    sum = reds[0] + reds[1] + reds[2] + reds[3];

    float inv = 1.f / sum;
    #pragma unroll
    for (int i = 0; i < 8; ++i)
        out[b * SEQ + t + (i << 8)] = vals[i] * inv;
}

// ---------------------------------------------------------------------------
extern "C" void kernel_launch(void* const* d_in, const int* in_sizes, int n_in,
                              void* d_out, int out_size, void* d_ws, size_t ws_size,
                              hipStream_t stream) {
    const float* dh  = (const float*)d_in[0];   // [32, 1024]
    const float* enc = (const float*)d_in[1];   // [2048, 32, 1024]
    const float* W   = (const float*)d_in[2];   // [1024, 1024]
    // d_in[3] = bias: unused (cancels under softmax shift invariance)

    float* ws       = (float*)d_ws;
    float* vpart    = ws;                                   // 16*32*1024 = 524288 f
    float* v        = vpart + PARTS * BATCH * SIZE;         // 32*1024    =  32768 f
    float* energies = v + BATCH * SIZE;                     // 32*2048    =  65536 f

    k_project <<<PARTS * BATCH * (SIZE / 4) / 256, 256, 0, stream>>>(dh, W, vpart);
    k_reduce  <<<BATCH * (SIZE / 4) / 256, 256, 0, stream>>>(vpart, v);
    k_energies<<<(BATCH * SEQ / 2) / 4, 256, 0, stream>>>(enc, v, energies);
    k_softmax <<<BATCH, 256, 0, stream>>>(energies, (float*)d_out);
}